// Round 3
// baseline (155.246 us; speedup 1.0000x reference)
//
#include <hip/hip_runtime.h>

// Problem constants
#define BB   4
#define CC   144
#define HW   4096      // 64*64
#define PTOT 16384     // BB*HW
#define EPSB 1e-5f

typedef __bf16 bf16;
typedef __bf16 bf16x8 __attribute__((ext_vector_type(8)));
typedef float  f32x4  __attribute__((ext_vector_type(4)));
typedef unsigned short U16;
typedef U16 u16x4 __attribute__((ext_vector_type(4)));
typedef U16 u16x8 __attribute__((ext_vector_type(8)));

#define MFMA __builtin_amdgcn_mfma_f32_16x16x32_bf16

// ---- workspace layout (bytes) ----
// xn2: bf16, channel-group-major: el = (g<<17) + p*8 + j, g = c>>3 (18 groups)
#define XN_OFF    0UL         // bf16 [18][16384][8]             4,718,592
#define WINF_OFF  76021760UL  // bf16 frag [4][5][64][8]  (BN-scale folded)
#define W1F_OFF   76042240UL  // bf16 frag [4][18][64][8] (BN-scale folded)
#define W2F_OFF   76115968UL  // bf16 frag [4][18][64][8] (BN-scale folded)
#define WOUTF_OFF 76189696UL  // bf16 frag [9][2][64][8]  (BN-scale folded)
#define BNP_OFF   76208128UL  // f32 [672] (only shift slots are consumed)

// ------------------------------------------------------------------
// K1 (merged prep): blocks 0..255 = L2-normalize -> xn2 group-major;
// blocks 256..418 = weight pack (BN scale folded) + BN shift fold.
__global__ __launch_bounds__(576) void k_prep(const float* __restrict__ x,
    const float* __restrict__ w_in, const float* __restrict__ w1,
    const float* __restrict__ w2,   const float* __restrict__ w_out,
    const float* g_in, const float* b_in, const float* m_in, const float* v_in,
    const float* g1,   const float* b1,   const float* m1,   const float* v1,
    const float* g2,   const float* b2,   const float* m2,   const float* v2,
    const float* g_out,const float* b_out,const float* m_out,const float* v_out,
    bf16* xn2, bf16* w_inf, bf16* w1f, bf16* w2f, bf16* w_outf, float* bnp)
{
    __shared__ float red[9][64];
    if (blockIdx.x < 256) {
        // ---- norm: 576 threads = 64 positions x 9 channel-quads ----
        int bh = blockIdx.x;
        int t = threadIdx.x, w = t & 63, cq = t >> 6;   // cq 0..8
        const float* px = x + ((size_t)(bh >> 6) * CC) * HW + (bh & 63) * 64 + w;
        float vals[16];
        float s = 0.f;
        #pragma unroll
        for (int i = 0; i < 16; i++) {
            float v = px[(size_t)(cq * 16 + i) * HW];
            vals[i] = v; s += v * v;
        }
        red[cq][w] = s;
        __syncthreads();
        float tot = 0.f;
        #pragma unroll
        for (int q = 0; q < 9; q++) tot += red[q][w];
        float inv = 1.f / fmaxf(sqrtf(tot), 1e-12f);
        size_t p = (size_t)bh * 64 + w;
        #pragma unroll
        for (int k = 0; k < 2; k++) {
            int g = cq * 2 + k;
            u16x8 pk;
            #pragma unroll
            for (int j = 0; j < 8; j++) {
                bf16 v = (bf16)(vals[k * 8 + j] * inv);
                pk[j] = *(U16*)&v;
            }
            *(u16x8*)(xn2 + (((size_t)g) << 17) + p * 8) = pk;
        }
        return;
    }
    // ---- pack path ----
    int t = (blockIdx.x - 256) * 576 + threadIdx.x;
    if (t < 10240) {                       // w_inf: k = c, padded 144->160
        int e = t, j = e & 7, lane = (e >> 3) & 63, r = e >> 9;
        int ks = r % 5, mt = r / 5;
        int o = mt * 16 + (lane & 15);
        int c = ks * 32 + ((lane >> 4) << 3) + j;
        float s = g_in[o] * rsqrtf(v_in[o] + EPSB);
        w_inf[e] = (c < 144) ? (bf16)(w_in[o * 144 + c] * s) : (bf16)0.f;
    } else if (t < 47104) {                // w1f: K=576, k = ij*64 + c
        int e = t - 10240, j = e & 7, lane = (e >> 3) & 63, r = e >> 9;
        int ks = r % 18, mt = r / 18;
        int o = mt * 16 + (lane & 15);
        int k = ks * 32 + ((lane >> 4) << 3) + j;
        int ij = k >> 6, c = k & 63;
        float s = g1[o] * rsqrtf(v1[o] + EPSB);
        w1f[e] = (bf16)(w1[(o * 64 + c) * 9 + ij] * s);
    } else if (t < 83968) {                // w2f: k = rs*64 + c2
        int e = t - 47104, j = e & 7, lane = (e >> 3) & 63, r = e >> 9;
        int ks = r % 18, mt = r / 18;
        int o = mt * 16 + (lane & 15);
        int k = ks * 32 + ((lane >> 4) << 3) + j;
        int rs = k >> 6, c2 = k & 63;
        float s = g2[o] * rsqrtf(v2[o] + EPSB);
        w2f[e] = (bf16)(w2[o * 576 + c2 * 9 + rs] * s);
    } else if (t < 93184) {                // w_outf: M=144 (9 mt), K=64 (2 ks)
        int e = t - 83968, j = e & 7, lane = (e >> 3) & 63, r = e >> 9;
        int ks = r & 1, mt = r >> 1;
        int o = mt * 16 + (lane & 15);
        int c = ks * 32 + ((lane >> 4) << 3) + j;
        float s = g_out[o] * rsqrtf(v_out[o] + EPSB);
        w_outf[e] = (bf16)(w_out[o * 64 + c] * s);
    } else if (t < 93856) {                // BN shift fold
        int i = t - 93184;
        const float *g, *bb, *mm, *vv; int c; bool is_t;
        if (i < 128)      { g=g_in; bb=b_in; mm=m_in; vv=v_in; c=i&63;        is_t=i>=64;  }
        else if (i < 256) { g=g1;   bb=b1;   mm=m1;   vv=v1;   c=(i-128)&63;  is_t=i>=192; }
        else if (i < 384) { g=g2;   bb=b2;   mm=m2;   vv=v2;   c=(i-256)&63;  is_t=i>=320; }
        else              { int ii=i-384; g=g_out; bb=b_out; mm=m_out; vv=v_out;
                            c = ii % 144; is_t = ii >= 144; }
        float s = g[c] * rsqrtf(vv[c] + EPSB);
        bnp[i] = is_t ? (bb[c] - mm[c] * s) : s;
    }
}

// ------------------------------------------------------------------
// K2: FUSED stage1 -> stage2 -> stage3 -> stage4 + final BN.
// (1) phase B batches its 5 neighbor loads before compute (1 L2 latency
// per kp, not 5); (2) phase C: wave = one 16-chan M-tile, all 9 rs
// (balanced 162 MFMA/wave) + ring-2 A prefetch; (3) phase D ring-2 A
// prefetch; (4) launch_bounds(256,3) pins 3 blocks/CU (LDS also allows 3).
__global__ __launch_bounds__(256, 3) void k_fused(const bf16* __restrict__ xn2,
        const bf16* __restrict__ w_inf, const bf16* __restrict__ w1f,
        const bf16* __restrict__ w2f,   const bf16* __restrict__ w_outf,
        const float* __restrict__ bnp,  float* __restrict__ out)
{
    __shared__ __align__(16) U16 lds[25600];   // 51200 B: a1 | (a2 + v3)
    U16* a2_lds = lds;                         // 9216 els, aliases a1
    U16* v3     = lds + 9216;                  // 1024 els

    const int LUT5c[9] = {0, 1, 2, 5, 6, 7, 10, 11, 12};

    int t = threadIdx.x, wid = t >> 6, lane = t & 63;
    int quad = lane >> 4, pl = lane & 15;
    int raw = blockIdx.x;
    int bid = (raw & 7) * 128 + (raw >> 3);    // XCD swizzle (1024 % 8 == 0)
    int p0 = bid * 16;
    int b = p0 >> 12, h = (p0 >> 6) & 63, hw0 = p0 & 4095;
    int wc = (p0 & 63) + pl;

    // ---- hoisted fragments / BN shifts ----
    bf16x8 af[4][5];
    #pragma unroll
    for (int mt = 0; mt < 4; mt++)
        #pragma unroll
        for (int ks = 0; ks < 5; ks++)
            af[mt][ks] = *(const bf16x8*)(w_inf + ((mt * 5 + ks) * 64 + lane) * 8);
    bf16x8 cfr[5];
    #pragma unroll
    for (int ks = 0; ks < 5; ks++) {
        int g = ks * 4 + quad;
        bf16x8 z = {};
        cfr[ks] = (g < 18) ? *(const bf16x8*)(xn2 + ((size_t)g << 17) + (size_t)(p0 + pl) * 8) : z;
    }
    f32x4 tv[4];
    #pragma unroll
    for (int mt = 0; mt < 4; mt++)
        tv[mt] = *(const f32x4*)&bnp[64 + mt * 16 + quad * 4];

    // ---- phase B: stage1. wave handles kp = wid, wid+4, ... ----
    for (int kp = wid; kp < 25; kp += 4) {
        int kpr = kp / 5, kpc = kp - kpr * 5;
        int dh = kpr - 2, dw = kpc - 2;
        bool ok = ((unsigned)(h + dh) < 64u) && ((unsigned)(wc + dw) < 64u);
        size_t pn = (size_t)(p0 + dh * 64 + dw + pl);
        bf16x8 nv[5];
        #pragma unroll
        for (int ks = 0; ks < 5; ks++) {       // batch all loads: 1 latency/kp
            int g = ks * 4 + quad;
            bf16x8 z = {};
            nv[ks] = (ok && g < 18) ? *(const bf16x8*)(xn2 + ((size_t)g << 17) + pn * 8) : z;
        }
        f32x4 acc[4] = {};
        #pragma unroll
        for (int ks = 0; ks < 5; ks++) {
            bf16x8 bfr;
            #pragma unroll
            for (int j = 0; j < 8; j++)
                bfr[j] = (bf16)((float)nv[ks][j] * (float)cfr[ks][j]);
            #pragma unroll
            for (int mt = 0; mt < 4; mt++)
                acc[mt] = MFMA(af[mt][ks], bfr, acc[mt], 0, 0, 0);
        }
        int swb = kp * 3 + pl;
        #pragma unroll
        for (int mt = 0; mt < 4; mt++) {
            u16x4 pk;
            #pragma unroll
            for (int r = 0; r < 4; r++) {
                bf16 v = (bf16)fmaxf(acc[mt][r] + tv[mt][r], 0.f);
                pk[r] = *(U16*)&v;
            }
            int g0 = mt * 2 + (quad >> 1);
            int dst = pl * 1600 + kp * 64 + (((g0 + swb) & 7) << 3) + (quad & 1) * 4;
            *(u16x4*)&lds[dst] = pk;
        }
    }
    __syncthreads();

    // ---- phase C: stage2. wave = one 16-chan M-tile (mt=wid), all 9 rs ----
    {
        int mt = wid;
        f32x4 acc2[9] = {};
        bf16x8 aaC[2];
        aaC[0] = *(const bf16x8*)(w1f + ((mt * 18 + 0) * 64 + lane) * 8);
        #pragma unroll
        for (int ks = 0; ks < 18; ks++) {
            if (ks + 1 < 18)                   // ring-2 A prefetch
                aaC[(ks + 1) & 1] = *(const bf16x8*)(w1f + ((mt * 18 + ks + 1) * 64 + lane) * 8);
            int ij = ks >> 1, gb = (ks & 1) * 4 + quad;
            int l5 = LUT5c[ij];
            bf16x8 bfr[9];
            #pragma unroll
            for (int rs = 0; rs < 9; rs++) {
                int kpidx = l5 + LUT5c[rs];
                int off = pl * 1600 + kpidx * 64 + (((gb + kpidx * 3 + pl) & 7) << 3);
                bfr[rs] = *(const bf16x8*)&lds[off];
            }
            #pragma unroll
            for (int rs = 0; rs < 9; rs++)
                acc2[rs] = MFMA(aaC[ks & 1], bfr[rs], acc2[rs], 0, 0, 0);
        }
        // epilogue C -> registers, then (after barrier) LDS a2 aliasing a1
        f32x4 t1v = *(const f32x4*)&bnp[192 + mt * 16 + quad * 4];
        u16x4 pk2[9];
        #pragma unroll
        for (int rs = 0; rs < 9; rs++) {
            #pragma unroll
            for (int r = 0; r < 4; r++) {
                bf16 v = (bf16)fmaxf(acc2[rs][r] + t1v[r], 0.f);
                pk2[rs][r] = *(U16*)&v;
            }
        }
        __syncthreads();                       // all waves done READING a1
        #pragma unroll
        for (int rs = 0; rs < 9; rs++) {
            int c = rs * 8 + mt * 2 + (quad >> 1);   // k-chunk of k=rs*64+ch
            int dst = pl * 576 + ((c >> 3) << 6) + ((((c & 7) + pl) & 7) << 3) + (quad & 1) * 4;
            *(u16x4*)&a2_lds[dst] = pk2[rs];
        }
    }
    __syncthreads();

    // ---- phase D: stage3 (M=64 split across 4 waves) ----
    {
        int mt = wid;
        f32x4 acc3 = {};
        bf16x8 aaD[2];
        aaD[0] = *(const bf16x8*)(w2f + ((mt * 18 + 0) * 64 + lane) * 8);
        #pragma unroll
        for (int ks = 0; ks < 18; ks++) {
            if (ks + 1 < 18)                   // ring-2 A prefetch
                aaD[(ks + 1) & 1] = *(const bf16x8*)(w2f + ((mt * 18 + ks + 1) * 64 + lane) * 8);
            int cg = ks * 4 + quad;
            int off = pl * 576 + ((cg >> 3) << 6) + ((((cg & 7) + pl) & 7) << 3);
            bf16x8 bfr = *(const bf16x8*)&a2_lds[off];
            acc3 = MFMA(aaD[ks & 1], bfr, acc3, 0, 0, 0);
        }
        #pragma unroll
        for (int r = 0; r < 4; r++) {
            int o = mt * 16 + quad * 4 + r;
            bf16 yb = (bf16)fmaxf(acc3[r] + bnp[320 + o], 0.f);
            v3[pl * 64 + ((((o >> 3) + pl) & 7) << 3) + (o & 7)] = *(U16*)&yb;
        }
    }
    __syncthreads();

    // ---- phase E: stage4 (M=144, 9 mt over 4 waves) + final BN -> out ----
    for (int mt = wid; mt < 9; mt += 4) {
        bf16x8 afr0 = *(const bf16x8*)(w_outf + ((mt * 2 + 0) * 64 + lane) * 8);
        bf16x8 afr1 = *(const bf16x8*)(w_outf + ((mt * 2 + 1) * 64 + lane) * 8);
        bf16x8 bfr0 = *(const bf16x8*)&v3[pl * 64 + ((((0 * 4 + quad) + pl) & 7) << 3)];
        bf16x8 bfr1 = *(const bf16x8*)&v3[pl * 64 + ((((1 * 4 + quad) + pl) & 7) << 3)];
        f32x4 accB = {};
        accB = MFMA(afr0, bfr0, accB, 0, 0, 0);
        accB = MFMA(afr1, bfr1, accB, 0, 0, 0);
        #pragma unroll
        for (int r = 0; r < 4; r++) {
            int oc = mt * 16 + quad * 4 + r;
            out[((size_t)(b * 144 + oc)) * 4096 + hw0 + pl] = accB[r] + bnp[528 + oc];
        }
    }
}

// ------------------------------------------------------------------
extern "C" void kernel_launch(void* const* d_in, const int* in_sizes, int n_in,
                              void* d_out, int out_size, void* d_ws, size_t ws_size,
                              hipStream_t stream)
{
    const float* x     = (const float*)d_in[0];
    const float* w_in  = (const float*)d_in[1];
    const float* g_in  = (const float*)d_in[2];
    const float* b_in  = (const float*)d_in[3];
    const float* m_in  = (const float*)d_in[4];
    const float* v_in  = (const float*)d_in[5];
    const float* w1    = (const float*)d_in[6];
    const float* g1    = (const float*)d_in[7];
    const float* b1    = (const float*)d_in[8];
    const float* m1    = (const float*)d_in[9];
    const float* v1    = (const float*)d_in[10];
    const float* w2    = (const float*)d_in[11];
    const float* g2    = (const float*)d_in[12];
    const float* b2    = (const float*)d_in[13];
    const float* m2    = (const float*)d_in[14];
    const float* v2    = (const float*)d_in[15];
    const float* w_out = (const float*)d_in[16];
    const float* g_out = (const float*)d_in[17];
    const float* b_out = (const float*)d_in[18];
    const float* m_out = (const float*)d_in[19];
    const float* v_out = (const float*)d_in[20];
    float* out = (float*)d_out;

    char* ws = (char*)d_ws;
    bf16*  xn2    = (bf16*)(ws + XN_OFF);
    bf16*  w_inf  = (bf16*)(ws + WINF_OFF);
    bf16*  w1f    = (bf16*)(ws + W1F_OFF);
    bf16*  w2f    = (bf16*)(ws + W2F_OFF);
    bf16*  w_outf = (bf16*)(ws + WOUTF_OFF);
    float* bnp    = (float*)(ws + BNP_OFF);

    hipLaunchKernelGGL(k_prep, dim3(419), dim3(576), 0, stream,
                       x, w_in, w1, w2, w_out,
                       g_in, b_in, m_in, v_in, g1, b1, m1, v1,
                       g2, b2, m2, v2, g_out, b_out, m_out, v_out,
                       xn2, w_inf, w1f, w2f, w_outf, bnp);
    hipLaunchKernelGGL(k_fused, dim3(1024), dim3(256), 0, stream,
                       xn2, w_inf, w1f, w2f, w_outf, bnp, out);
}

// Round 4
// 128.307 us; speedup vs baseline: 1.2100x; 1.2100x over previous
//
#include <hip/hip_runtime.h>

// Problem constants
#define BB   4
#define CC   144
#define HW   4096      // 64*64
#define PTOT 16384     // BB*HW
#define EPSB 1e-5f

typedef __bf16 bf16;
typedef __bf16 bf16x8 __attribute__((ext_vector_type(8)));
typedef float  f32x4  __attribute__((ext_vector_type(4)));
typedef unsigned short U16;
typedef U16 u16x4 __attribute__((ext_vector_type(4)));
typedef U16 u16x8 __attribute__((ext_vector_type(8)));

#define MFMA __builtin_amdgcn_mfma_f32_16x16x32_bf16

// ---- workspace layout (bytes) ----
// xn2: bf16, channel-group-major: el = (g<<17) + p*8 + j, g = c>>3 (18 groups)
#define XN_OFF    0UL         // bf16 [18][16384][8]             4,718,592
#define WINF_OFF  76021760UL  // bf16 frag [4][5][64][8]  (BN-scale folded)
#define W1F_OFF   76042240UL  // bf16 frag [4][18][64][8] (BN-scale folded)
#define W2F_OFF   76115968UL  // bf16 frag [4][18][64][8] (BN-scale folded)
#define WOUTF_OFF 76189696UL  // bf16 frag [9][2][64][8]  (BN-scale folded)
#define BNP_OFF   76208128UL  // f32 [672] (only shift slots are consumed)

// ------------------------------------------------------------------
// K1 (merged prep): blocks 0..255 = L2-normalize -> xn2 group-major;
// blocks 256..418 = weight pack (BN scale folded) + BN shift fold.
__global__ __launch_bounds__(576) void k_prep(const float* __restrict__ x,
    const float* __restrict__ w_in, const float* __restrict__ w1,
    const float* __restrict__ w2,   const float* __restrict__ w_out,
    const float* g_in, const float* b_in, const float* m_in, const float* v_in,
    const float* g1,   const float* b1,   const float* m1,   const float* v1,
    const float* g2,   const float* b2,   const float* m2,   const float* v2,
    const float* g_out,const float* b_out,const float* m_out,const float* v_out,
    bf16* xn2, bf16* w_inf, bf16* w1f, bf16* w2f, bf16* w_outf, float* bnp)
{
    __shared__ float red[9][64];
    if (blockIdx.x < 256) {
        // ---- norm: 576 threads = 64 positions x 9 channel-quads ----
        int bh = blockIdx.x;
        int t = threadIdx.x, w = t & 63, cq = t >> 6;   // cq 0..8
        const float* px = x + ((size_t)(bh >> 6) * CC) * HW + (bh & 63) * 64 + w;
        float vals[16];
        float s = 0.f;
        #pragma unroll
        for (int i = 0; i < 16; i++) {
            float v = px[(size_t)(cq * 16 + i) * HW];
            vals[i] = v; s += v * v;
        }
        red[cq][w] = s;
        __syncthreads();
        float tot = 0.f;
        #pragma unroll
        for (int q = 0; q < 9; q++) tot += red[q][w];
        float inv = 1.f / fmaxf(sqrtf(tot), 1e-12f);
        size_t p = (size_t)bh * 64 + w;
        #pragma unroll
        for (int k = 0; k < 2; k++) {
            int g = cq * 2 + k;
            u16x8 pk;
            #pragma unroll
            for (int j = 0; j < 8; j++) {
                bf16 v = (bf16)(vals[k * 8 + j] * inv);
                pk[j] = *(U16*)&v;
            }
            *(u16x8*)(xn2 + (((size_t)g) << 17) + p * 8) = pk;
        }
        return;
    }
    // ---- pack path ----
    int t = (blockIdx.x - 256) * 576 + threadIdx.x;
    if (t < 10240) {                       // w_inf: k = c, padded 144->160
        int e = t, j = e & 7, lane = (e >> 3) & 63, r = e >> 9;
        int ks = r % 5, mt = r / 5;
        int o = mt * 16 + (lane & 15);
        int c = ks * 32 + ((lane >> 4) << 3) + j;
        float s = g_in[o] * rsqrtf(v_in[o] + EPSB);
        w_inf[e] = (c < 144) ? (bf16)(w_in[o * 144 + c] * s) : (bf16)0.f;
    } else if (t < 47104) {                // w1f: K=576, k = ij*64 + c
        int e = t - 10240, j = e & 7, lane = (e >> 3) & 63, r = e >> 9;
        int ks = r % 18, mt = r / 18;
        int o = mt * 16 + (lane & 15);
        int k = ks * 32 + ((lane >> 4) << 3) + j;
        int ij = k >> 6, c = k & 63;
        float s = g1[o] * rsqrtf(v1[o] + EPSB);
        w1f[e] = (bf16)(w1[(o * 64 + c) * 9 + ij] * s);
    } else if (t < 83968) {                // w2f: k = rs*64 + c2
        int e = t - 47104, j = e & 7, lane = (e >> 3) & 63, r = e >> 9;
        int ks = r % 18, mt = r / 18;
        int o = mt * 16 + (lane & 15);
        int k = ks * 32 + ((lane >> 4) << 3) + j;
        int rs = k >> 6, c2 = k & 63;
        float s = g2[o] * rsqrtf(v2[o] + EPSB);
        w2f[e] = (bf16)(w2[o * 576 + c2 * 9 + rs] * s);
    } else if (t < 93184) {                // w_outf: M=144 (9 mt), K=64 (2 ks)
        int e = t - 83968, j = e & 7, lane = (e >> 3) & 63, r = e >> 9;
        int ks = r & 1, mt = r >> 1;
        int o = mt * 16 + (lane & 15);
        int c = ks * 32 + ((lane >> 4) << 3) + j;
        float s = g_out[o] * rsqrtf(v_out[o] + EPSB);
        w_outf[e] = (bf16)(w_out[o * 64 + c] * s);
    } else if (t < 93856) {                // BN shift fold
        int i = t - 93184;
        const float *g, *bb, *mm, *vv; int c; bool is_t;
        if (i < 128)      { g=g_in; bb=b_in; mm=m_in; vv=v_in; c=i&63;        is_t=i>=64;  }
        else if (i < 256) { g=g1;   bb=b1;   mm=m1;   vv=v1;   c=(i-128)&63;  is_t=i>=192; }
        else if (i < 384) { g=g2;   bb=b2;   mm=m2;   vv=v2;   c=(i-256)&63;  is_t=i>=320; }
        else              { int ii=i-384; g=g_out; bb=b_out; mm=m_out; vv=v_out;
                            c = ii % 144; is_t = ii >= 144; }
        float s = g[c] * rsqrtf(vv[c] + EPSB);
        bnp[i] = is_t ? (bb[c] - mm[c] * s) : s;
    }
}

// ------------------------------------------------------------------
// K2: FUSED stage1 -> stage2 -> stage3 -> stage4 + final BN.
// vs R3: no occupancy pin (spill fix); phase C = preloaded A[18] + 3
// chunks of 3 rs (12-VGPR inner live set); phase D A[18] preloaded
// behind the a2 barriers; phase E A prefetched behind phase D barrier.
__global__ __launch_bounds__(256) void k_fused(const bf16* __restrict__ xn2,
        const bf16* __restrict__ w_inf, const bf16* __restrict__ w1f,
        const bf16* __restrict__ w2f,   const bf16* __restrict__ w_outf,
        const float* __restrict__ bnp,  float* __restrict__ out)
{
    __shared__ __align__(16) U16 lds[25600];   // 51200 B: a1 | (a2 + v3)
    U16* a2_lds = lds;                         // 9216 els, aliases a1
    U16* v3     = lds + 9216;                  // 1024 els

    const int LUT5c[9] = {0, 1, 2, 5, 6, 7, 10, 11, 12};

    int t = threadIdx.x, wid = t >> 6, lane = t & 63;
    int quad = lane >> 4, pl = lane & 15;
    int raw = blockIdx.x;
    int bid = (raw & 7) * 128 + (raw >> 3);    // XCD swizzle (1024 % 8 == 0)
    int p0 = bid * 16;
    int b = p0 >> 12, h = (p0 >> 6) & 63, hw0 = p0 & 4095;
    int wc = (p0 & 63) + pl;

    // ---- hoisted fragments / BN shifts ----
    bf16x8 af[4][5];
    #pragma unroll
    for (int mt = 0; mt < 4; mt++)
        #pragma unroll
        for (int ks = 0; ks < 5; ks++)
            af[mt][ks] = *(const bf16x8*)(w_inf + ((mt * 5 + ks) * 64 + lane) * 8);
    bf16x8 cfr[5];
    #pragma unroll
    for (int ks = 0; ks < 5; ks++) {
        int g = ks * 4 + quad;
        bf16x8 z = {};
        cfr[ks] = (g < 18) ? *(const bf16x8*)(xn2 + ((size_t)g << 17) + (size_t)(p0 + pl) * 8) : z;
    }
    f32x4 tv[4];
    #pragma unroll
    for (int mt = 0; mt < 4; mt++)
        tv[mt] = *(const f32x4*)&bnp[64 + mt * 16 + quad * 4];

    // ---- phase B: stage1. wave handles kp = wid, wid+4, ... ----
    for (int kp = wid; kp < 25; kp += 4) {
        int kpr = kp / 5, kpc = kp - kpr * 5;
        int dh = kpr - 2, dw = kpc - 2;
        bool ok = ((unsigned)(h + dh) < 64u) && ((unsigned)(wc + dw) < 64u);
        size_t pn = (size_t)(p0 + dh * 64 + dw + pl);
        bf16x8 nv[5];
        #pragma unroll
        for (int ks = 0; ks < 5; ks++) {       // batch all loads: 1 latency/kp
            int g = ks * 4 + quad;
            bf16x8 z = {};
            nv[ks] = (ok && g < 18) ? *(const bf16x8*)(xn2 + ((size_t)g << 17) + pn * 8) : z;
        }
        f32x4 acc[4] = {};
        #pragma unroll
        for (int ks = 0; ks < 5; ks++) {
            bf16x8 bfr;
            #pragma unroll
            for (int j = 0; j < 8; j++)
                bfr[j] = (bf16)((float)nv[ks][j] * (float)cfr[ks][j]);
            #pragma unroll
            for (int mt = 0; mt < 4; mt++)
                acc[mt] = MFMA(af[mt][ks], bfr, acc[mt], 0, 0, 0);
        }
        int swb = kp * 3 + pl;
        #pragma unroll
        for (int mt = 0; mt < 4; mt++) {
            u16x4 pk;
            #pragma unroll
            for (int r = 0; r < 4; r++) {
                bf16 v = (bf16)fmaxf(acc[mt][r] + tv[mt][r], 0.f);
                pk[r] = *(U16*)&v;
            }
            int g0 = mt * 2 + (quad >> 1);
            int dst = pl * 1600 + kp * 64 + (((g0 + swb) & 7) << 3) + (quad & 1) * 4;
            *(u16x4*)&lds[dst] = pk;
        }
    }
    __syncthreads();

    // ---- phase C: stage2. wave = one 16-chan M-tile; A[18] preloaded;
    //      9 rs processed in 3 chunks of 3 (small live set, no spill) ----
    u16x4 pk2[9];
    {
        int mt = wid;
        bf16x8 aaC[18];
        #pragma unroll
        for (int ks = 0; ks < 18; ks++)        // one batched L2 latency
            aaC[ks] = *(const bf16x8*)(w1f + ((mt * 18 + ks) * 64 + lane) * 8);
        f32x4 t1v = *(const f32x4*)&bnp[192 + mt * 16 + quad * 4];
        #pragma unroll
        for (int ch = 0; ch < 3; ch++) {
            f32x4 acc[3] = {};
            #pragma unroll
            for (int ks = 0; ks < 18; ks++) {
                int gb = (ks & 1) * 4 + quad;
                int l5 = LUT5c[ks >> 1];
                #pragma unroll
                for (int i = 0; i < 3; i++) {
                    int kpidx = l5 + LUT5c[ch * 3 + i];
                    int off = pl * 1600 + kpidx * 64 + (((gb + kpidx * 3 + pl) & 7) << 3);
                    bf16x8 bfr = *(const bf16x8*)&lds[off];
                    acc[i] = MFMA(aaC[ks], bfr, acc[i], 0, 0, 0);
                }
            }
            #pragma unroll
            for (int i = 0; i < 3; i++) {
                #pragma unroll
                for (int r = 0; r < 4; r++) {
                    bf16 v = (bf16)fmaxf(acc[i][r] + t1v[r], 0.f);
                    pk2[ch * 3 + i][r] = *(U16*)&v;
                }
            }
        }
    }
    __syncthreads();                           // all waves done READING a1

    // phase D A-fragments: issue now, latency drains during barrier wait
    bf16x8 aaD[18];
    #pragma unroll
    for (int ks = 0; ks < 18; ks++)
        aaD[ks] = *(const bf16x8*)(w2f + ((wid * 18 + ks) * 64 + lane) * 8);
    {
        int mt = wid;
        #pragma unroll
        for (int rs = 0; rs < 9; rs++) {
            int c = rs * 8 + mt * 2 + (quad >> 1);   // k-chunk of k=rs*64+ch
            int dst = pl * 576 + ((c >> 3) << 6) + ((((c & 7) + pl) & 7) << 3) + (quad & 1) * 4;
            *(u16x4*)&a2_lds[dst] = pk2[rs];
        }
    }
    __syncthreads();

    // ---- phase D: stage3 (M=64 split across 4 waves) ----
    {
        int mt = wid;
        f32x4 acc3 = {};
        #pragma unroll
        for (int ks = 0; ks < 18; ks++) {
            int cg = ks * 4 + quad;
            int off = pl * 576 + ((cg >> 3) << 6) + ((((cg & 7) + pl) & 7) << 3);
            bf16x8 bfr = *(const bf16x8*)&a2_lds[off];
            acc3 = MFMA(aaD[ks], bfr, acc3, 0, 0, 0);
        }
        #pragma unroll
        for (int r = 0; r < 4; r++) {
            int o = mt * 16 + quad * 4 + r;
            bf16 yb = (bf16)fmaxf(acc3[r] + bnp[320 + o], 0.f);
            v3[pl * 64 + ((((o >> 3) + pl) & 7) << 3) + (o & 7)] = *(U16*)&yb;
        }
    }
    // phase E A-fragments: issue before the barrier (latency hidden)
    bf16x8 afrE[3][2];
    #pragma unroll
    for (int q = 0; q < 3; q++) {
        int mt = wid + q * 4;
        if (mt < 9) {
            afrE[q][0] = *(const bf16x8*)(w_outf + ((mt * 2 + 0) * 64 + lane) * 8);
            afrE[q][1] = *(const bf16x8*)(w_outf + ((mt * 2 + 1) * 64 + lane) * 8);
        }
    }
    __syncthreads();

    // ---- phase E: stage4 (M=144, 9 mt over 4 waves) + final BN -> out ----
    bf16x8 bfr0 = *(const bf16x8*)&v3[pl * 64 + (((quad + pl) & 7) << 3)];
    bf16x8 bfr1 = *(const bf16x8*)&v3[pl * 64 + ((((4 + quad) + pl) & 7) << 3)];
    #pragma unroll
    for (int q = 0; q < 3; q++) {
        int mt = wid + q * 4;
        if (mt < 9) {
            f32x4 accB = {};
            accB = MFMA(afrE[q][0], bfr0, accB, 0, 0, 0);
            accB = MFMA(afrE[q][1], bfr1, accB, 0, 0, 0);
            #pragma unroll
            for (int r = 0; r < 4; r++) {
                int oc = mt * 16 + quad * 4 + r;
                out[((size_t)(b * 144 + oc)) * 4096 + hw0 + pl] = accB[r] + bnp[528 + oc];
            }
        }
    }
}

// ------------------------------------------------------------------
extern "C" void kernel_launch(void* const* d_in, const int* in_sizes, int n_in,
                              void* d_out, int out_size, void* d_ws, size_t ws_size,
                              hipStream_t stream)
{
    const float* x     = (const float*)d_in[0];
    const float* w_in  = (const float*)d_in[1];
    const float* g_in  = (const float*)d_in[2];
    const float* b_in  = (const float*)d_in[3];
    const float* m_in  = (const float*)d_in[4];
    const float* v_in  = (const float*)d_in[5];
    const float* w1    = (const float*)d_in[6];
    const float* g1    = (const float*)d_in[7];
    const float* b1    = (const float*)d_in[8];
    const float* m1    = (const float*)d_in[9];
    const float* v1    = (const float*)d_in[10];
    const float* w2    = (const float*)d_in[11];
    const float* g2    = (const float*)d_in[12];
    const float* b2    = (const float*)d_in[13];
    const float* m2    = (const float*)d_in[14];
    const float* v2    = (const float*)d_in[15];
    const float* w_out = (const float*)d_in[16];
    const float* g_out = (const float*)d_in[17];
    const float* b_out = (const float*)d_in[18];
    const float* m_out = (const float*)d_in[19];
    const float* v_out = (const float*)d_in[20];
    float* out = (float*)d_out;

    char* ws = (char*)d_ws;
    bf16*  xn2    = (bf16*)(ws + XN_OFF);
    bf16*  w_inf  = (bf16*)(ws + WINF_OFF);
    bf16*  w1f    = (bf16*)(ws + W1F_OFF);
    bf16*  w2f    = (bf16*)(ws + W2F_OFF);
    bf16*  w_outf = (bf16*)(ws + WOUTF_OFF);
    float* bnp    = (float*)(ws + BNP_OFF);

    hipLaunchKernelGGL(k_prep, dim3(419), dim3(576), 0, stream,
                       x, w_in, w1, w2, w_out,
                       g_in, b_in, m_in, v_in, g1, b1, m1, v1,
                       g2, b2, m2, v2, g_out, b_out, m_out, v_out,
                       xn2, w_inf, w1f, w2f, w_outf, bnp);
    hipLaunchKernelGGL(k_fused, dim3(1024), dim3(256), 0, stream,
                       xn2, w_inf, w1f, w2f, w_outf, bnp, out);
}